// Round 1
// baseline (1287.701 us; speedup 1.0000x reference)
//
#include <hip/hip_runtime.h>
#include <cstdint>
#include <cstddef>

#define N_P 2048
#define N_W 89
#define N_ALLC 2137
#define BQ 16384
#define E2C 768

// ---------------- reduce helpers ----------------
__device__ __forceinline__ float waveMax(float v){
#pragma unroll
  for (int o = 32; o > 0; o >>= 1) v = fmaxf(v, __shfl_down(v, o, 64));
  return v;
}
__device__ __forceinline__ float waveSum(float v){
#pragma unroll
  for (int o = 32; o > 0; o >>= 1) v += __shfl_down(v, o, 64);
  return v;
}

// ---------------- repack w (8,256,32) -> row-major (256,256) ----------------
__global__ __launch_bounds__(256) void repack_w(const float* __restrict__ w,
                                                float* __restrict__ wrm) {
  int idx = blockIdx.x * 256 + threadIdx.x;           // < 65536
  int f = idx >> 8, c = idx & 255;
  int h = c >> 5, o = c & 31;
  wrm[idx] = w[h * 8192 + f * 32 + o];
}

// ---------------- copy word_feature into h1wp rows 0..88 ----------------
__global__ __launch_bounds__(256) void copy_word(const float* __restrict__ wf,
                                                 float* __restrict__ h1wp) {
  int idx = blockIdx.x * 256 + threadIdx.x;
  if (idx < N_W * 256) h1wp[idx] = wf[idx];
}

// ---------------- generic f32 GEMM: C[M,N] = A[M,K]@B[K,N] + bias ----------------
// BM=BN=64, BK=16, 256 threads, 4x4 per thread. N%64==0, K%16==0, M guarded.
__global__ __launch_bounds__(256) void gemm_f32(
    const float* __restrict__ A, int lda,
    const float* __restrict__ B, int ldb,
    float* __restrict__ C, int ldc,
    const float* __restrict__ bias,
    int M, int N, int K, int relu)
{
  __shared__ __align__(16) float As[16][68];
  __shared__ __align__(16) float Bs[16][68];
  int t = threadIdx.x;
  int m0 = blockIdx.x * 64, n0 = blockIdx.y * 64;
  int tm = t >> 4, tn = t & 15;
  int ar = t >> 2, ak = (t & 3) * 4;
  int bk = t >> 4, bn = (t & 15) * 4;
  float acc[4][4] = {};
  for (int k0 = 0; k0 < K; k0 += 16) {
    float4 av = {0.f, 0.f, 0.f, 0.f};
    int arow = m0 + ar;
    if (arow < M) av = *(const float4*)(A + (size_t)arow * lda + k0 + ak);
    As[ak][ar] = av.x; As[ak + 1][ar] = av.y; As[ak + 2][ar] = av.z; As[ak + 3][ar] = av.w;
    *(float4*)&Bs[bk][bn] = *(const float4*)(B + (size_t)(k0 + bk) * ldb + n0 + bn);
    __syncthreads();
#pragma unroll
    for (int kk = 0; kk < 16; ++kk) {
      float4 a4 = *(const float4*)&As[kk][tm * 4];
      float4 b4 = *(const float4*)&Bs[kk][tn * 4];
      float a[4] = {a4.x, a4.y, a4.z, a4.w};
      float b[4] = {b4.x, b4.y, b4.z, b4.w};
#pragma unroll
      for (int i = 0; i < 4; ++i)
#pragma unroll
        for (int j = 0; j < 4; ++j) acc[i][j] += a[i] * b[j];
    }
    __syncthreads();
  }
  float4 bb = {0.f, 0.f, 0.f, 0.f};
  if (bias) bb = *(const float4*)(bias + n0 + tn * 4);
  float bbv[4] = {bb.x, bb.y, bb.z, bb.w};
#pragma unroll
  for (int i = 0; i < 4; ++i) {
    int row = m0 + tm * 4 + i;
    if (row < M) {
      float4 v;
      float r0 = acc[i][0] + bbv[0], r1 = acc[i][1] + bbv[1];
      float r2 = acc[i][2] + bbv[2], r3 = acc[i][3] + bbv[3];
      if (relu) { r0 = fmaxf(r0, 0.f); r1 = fmaxf(r1, 0.f); r2 = fmaxf(r2, 0.f); r3 = fmaxf(r3, 0.f); }
      v.x = r0; v.y = r1; v.z = r2; v.w = r3;
      *(float4*)(C + (size_t)row * ldc + n0 + tn * 4) = v;
    }
  }
}

// ---------------- e_src / e_dst: dot(hp[n, h*32..], a) ----------------
__global__ __launch_bounds__(256) void esrc_edst(
    const float* __restrict__ hp,       // [N][256] (n, h*32+o)
    const float* __restrict__ a_src,    // [8][32]
    const float* __restrict__ a_dst,    // [8][32]
    float* __restrict__ es, float* __restrict__ ed, int N)
{
  __shared__ float sa[256], sd[256];
  int t = threadIdx.x;
  sa[t] = a_src[t]; sd[t] = a_dst[t];
  __syncthreads();
  int idx = blockIdx.x * 256 + t;
  if (idx >= N * 8) return;
  int n = idx >> 3, h = idx & 7;
  const float* hpp = hp + (size_t)n * 256 + h * 32;
  const float* ap = sa + h * 32;
  const float* dp = sd + h * 32;
  float s = 0.f, d = 0.f;
#pragma unroll
  for (int o = 0; o < 32; ++o) { float v = hpp[o]; s += v * ap[o]; d += v * dp[o]; }
  es[h * N + n] = s; ed[h * N + n] = d;
}

// ---------------- GAT1 attention: softmax rows, write attn_pp ----------------
__global__ __launch_bounds__(256) void gat_attn1(
    const float* __restrict__ es, const float* __restrict__ ed,   // [8][2048]
    const int* __restrict__ adj,                                  // [2048][2048]
    float* __restrict__ attn)                                     // [8][2048][2048]
{
  __shared__ float val[N_P];
  __shared__ float adjf[N_P];
  __shared__ float red[4];
  int t = threadIdx.x, n = blockIdx.x;
  int lane = t & 63, wid = t >> 6;
  for (int m = t; m < N_P; m += 256) adjf[m] = (adj[(size_t)n * N_P + m] > 0) ? 1.f : 0.f;
  __syncthreads();
  for (int h = 0; h < 8; ++h) {
    float esv = es[h * N_P + n];
    const float* edh = ed + h * N_P;
    float lmax = -3e38f;
    for (int m = t; m < N_P; m += 256) {
      float v = esv + edh[m];
      v = (v >= 0.f) ? v : 0.2f * v;
      v = (adjf[m] != 0.f) ? v : -1e9f;
      val[m] = v; lmax = fmaxf(lmax, v);
    }
    lmax = waveMax(lmax);
    if (lane == 0) red[wid] = lmax;
    __syncthreads();
    float gmax = fmaxf(fmaxf(red[0], red[1]), fmaxf(red[2], red[3]));
    __syncthreads();
    float lsum = 0.f;
    for (int m = t; m < N_P; m += 256) {
      float p = __expf(val[m] - gmax);
      val[m] = p; lsum += p;
    }
    lsum = waveSum(lsum);
    if (lane == 0) red[wid] = lsum;
    __syncthreads();
    float inv = 1.f / (red[0] + red[1] + red[2] + red[3]);
    float* arow = attn + ((size_t)h * N_P + n) * N_P;
    for (int m = t; m < N_P; m += 256) arow[m] = val[m] * inv;
    __syncthreads();
  }
}

// ---------------- PV GEMM for GAT1: h1wp[89+m] = elu(attn@hp + bias) ----------------
// grid (32, 8): 64 rows per block, one head. BK=32, thread tile 2x4.
__global__ __launch_bounds__(256) void pv_gemm1(
    const float* __restrict__ attn,   // [8][2048][2048]
    const float* __restrict__ hp,     // [2048][256]
    const float* __restrict__ bias,   // [32]
    float* __restrict__ h1wp)         // [2137][256]
{
  __shared__ __align__(16) float As[32][66];   // [kk][m]
  __shared__ __align__(16) float Bs[32][36];   // [kk][o]
  int t = threadIdx.x;
  int h = blockIdx.y;
  int m0 = blockIdx.x * 64;
  int tm = t >> 3, tn = t & 7;
  float acc[2][4] = {};
  const float* abase = attn + ((size_t)h * N_P + m0) * N_P;
  for (int k0 = 0; k0 < N_P; k0 += 32) {
    for (int idx = t; idx < 64 * 32; idx += 256) {
      int r = idx >> 5, c = idx & 31;
      As[c][r] = abase[(size_t)r * N_P + k0 + c];
    }
    for (int idx = t; idx < 32 * 32; idx += 256) {
      int r = idx >> 5, c = idx & 31;
      Bs[r][c] = hp[(size_t)(k0 + r) * 256 + h * 32 + c];
    }
    __syncthreads();
#pragma unroll
    for (int kk = 0; kk < 32; ++kk) {
      float2 a2 = *(const float2*)&As[kk][tm * 2];
      float4 b4 = *(const float4*)&Bs[kk][tn * 4];
      acc[0][0] += a2.x * b4.x; acc[0][1] += a2.x * b4.y; acc[0][2] += a2.x * b4.z; acc[0][3] += a2.x * b4.w;
      acc[1][0] += a2.y * b4.x; acc[1][1] += a2.y * b4.y; acc[1][2] += a2.y * b4.z; acc[1][3] += a2.y * b4.w;
    }
    __syncthreads();
  }
  float4 bv = *(const float4*)(bias + tn * 4);
  float bvv[4] = {bv.x, bv.y, bv.z, bv.w};
#pragma unroll
  for (int i = 0; i < 2; ++i) {
    int row = m0 + tm * 2 + i;
    float4 o;
    float r0 = acc[i][0] + bvv[0], r1 = acc[i][1] + bvv[1];
    float r2 = acc[i][2] + bvv[2], r3 = acc[i][3] + bvv[3];
    o.x = (r0 > 0.f) ? r0 : expm1f(r0);
    o.y = (r1 > 0.f) ? r1 : expm1f(r1);
    o.z = (r2 > 0.f) ? r2 : expm1f(r2);
    o.w = (r3 > 0.f) ? r3 : expm1f(r3);
    *(float4*)(h1wp + (size_t)(N_W + row) * 256 + h * 32 + tn * 4) = o;
  }
}

// ---------------- GAT2 attention + PV for word rows, h2w mean ----------------
__global__ __launch_bounds__(256) void gat_attn2(
    const float* __restrict__ hp,                                  // [2137][256]
    const float* __restrict__ es, const float* __restrict__ ed,    // [8][2137]
    const int* __restrict__ adj,                                   // [2137][2137]
    const float* __restrict__ bias,                                // [32]
    float* __restrict__ attn,                                      // [8][2137][2137]
    float* __restrict__ h2w)                                       // [89][32]
{
  __shared__ float val[2144];
  __shared__ float adjf[2144];
  __shared__ float red[4];
  __shared__ float pv[8][33];
  int t = threadIdx.x, n = blockIdx.x;
  int lane = t & 63, wid = t >> 6;
  for (int m = t; m < N_ALLC; m += 256) adjf[m] = (adj[(size_t)n * N_ALLC + m] > 0) ? 1.f : 0.f;
  __syncthreads();
  float h2acc = 0.f;
  for (int h = 0; h < 8; ++h) {
    float esv = es[h * N_ALLC + n];
    const float* edh = ed + h * N_ALLC;
    float lmax = -3e38f;
    for (int m = t; m < N_ALLC; m += 256) {
      float v = esv + edh[m];
      v = (v >= 0.f) ? v : 0.2f * v;
      v = (adjf[m] != 0.f) ? v : -1e9f;
      val[m] = v; lmax = fmaxf(lmax, v);
    }
    lmax = waveMax(lmax);
    if (lane == 0) red[wid] = lmax;
    __syncthreads();
    float gmax = fmaxf(fmaxf(red[0], red[1]), fmaxf(red[2], red[3]));
    __syncthreads();
    float lsum = 0.f;
    for (int m = t; m < N_ALLC; m += 256) {
      float p = __expf(val[m] - gmax);
      val[m] = p; lsum += p;
    }
    lsum = waveSum(lsum);
    if (lane == 0) red[wid] = lsum;
    __syncthreads();
    float inv = 1.f / (red[0] + red[1] + red[2] + red[3]);
    float* arow = attn + ((size_t)h * N_ALLC + n) * N_ALLC;
    for (int m = t; m < N_ALLC; m += 256) arow[m] = val[m] * inv;
    if (n < N_W) {                      // block-uniform branch
      int g = t >> 5, o = t & 31;
      float acc = 0.f;
      for (int m = g; m < N_ALLC; m += 8) acc += val[m] * hp[(size_t)m * 256 + h * 32 + o];
      pv[g][o] = acc;
      __syncthreads();
      if (t < 32) {
        float s = 0.f;
#pragma unroll
        for (int gg = 0; gg < 8; ++gg) s += pv[gg][t];
        h2acc += s * inv + bias[t];
      }
    }
    __syncthreads();
  }
  if (n < N_W && t < 32) h2w[n * 32 + t] = h2acc * 0.125f;
}

// ---------------- x: head matmul + concat + row-normalize ----------------
__global__ __launch_bounds__(256) void xnorm_kernel(
    const float* __restrict__ uwa,   // [B][313]
    const float* __restrict__ h2w,   // [89][32]
    float* __restrict__ xout)        // [B][256]
{
  __shared__ float urow[4][320];
  __shared__ float xh[4][33];
  __shared__ float inv[4];
  int t = threadIdx.x;
  int b0 = blockIdx.x * 4;
  for (int idx = t; idx < 4 * 313; idx += 256) {
    int r = idx / 313, j = idx - r * 313;
    urow[r][j] = uwa[(size_t)(b0 + r) * 313 + j];
  }
  __syncthreads();
  if (t < 128) {
    int r = t >> 5, o = t & 31;
    float s = 0.f;
    for (int i = 0; i < N_W; ++i) s += urow[r][i] * h2w[i * 32 + o];
    xh[r][o] = s;
  }
  __syncthreads();
  int lane = t & 63, w = t >> 6;
  float ls = 0.f;
  for (int c = lane; c < 256; c += 64) {
    float v = (c < 32) ? xh[w][c] : urow[w][89 + c - 32];
    ls += v;
  }
  ls = waveSum(ls);
  if (lane == 0) inv[w] = 1.f / ls;
  __syncthreads();
  for (int idx = t; idx < 1024; idx += 256) {
    int r = idx >> 8, c = idx & 255;
    float v = (c < 32) ? xh[r][c] : urow[r][89 + c - 32];
    xout[(size_t)(b0 + r) * 256 + c] = v * inv[r];
  }
}

// ---------------- final tiny GEMM: xtemp = t[B,128] @ Wfb[128,5] + bfb ----------------
__global__ __launch_bounds__(256) void final5(
    const float* __restrict__ tb,   // [B][128]
    const float* __restrict__ Wfb,  // [128][5]
    const float* __restrict__ bfb,  // [5]
    float* __restrict__ out)        // [B][5]
{
  __shared__ float tt[32][129];
  __shared__ float wfb[5][128];
  int t = threadIdx.x;
  int b0 = blockIdx.x * 32;
  for (int idx = t; idx < 32 * 128; idx += 256) {
    int r = idx >> 7, c = idx & 127;
    tt[r][c] = tb[(size_t)(b0 + r) * 128 + c];
  }
  for (int idx = t; idx < 640; idx += 256) {
    int q = idx >> 7, j = idx & 127;
    wfb[q][j] = Wfb[j * 5 + q];
  }
  __syncthreads();
  if (t < 160) {
    int q = t >> 5, r = t & 31;
    float s = bfb[q];
    const float* wq = wfb[q];
    for (int j = 0; j < 128; ++j) s += tt[r][j] * wq[j];
    out[(size_t)(b0 + r) * 5 + q] = s;
  }
}

extern "C" void kernel_launch(void* const* d_in, const int* in_sizes, int n_in,
                              void* d_out, int out_size, void* d_ws, size_t ws_size,
                              hipStream_t stream)
{
  const float* pf   = (const float*)d_in[0];
  const float* wf   = (const float*)d_in[1];
  const int*   adj1 = (const int*)d_in[2];
  const int*   adj2 = (const int*)d_in[3];
  const float* uwa  = (const float*)d_in[4];
  const float* sent = (const float*)d_in[5];
  const float* w1   = (const float*)d_in[6];
  const float* as1  = (const float*)d_in[7];
  const float* ad1  = (const float*)d_in[8];
  const float* b1   = (const float*)d_in[9];
  const float* w2   = (const float*)d_in[10];
  const float* as2  = (const float*)d_in[11];
  const float* ad2  = (const float*)d_in[12];
  const float* b2   = (const float*)d_in[13];
  const float* Ws1  = (const float*)d_in[14];
  const float* bs1  = (const float*)d_in[15];
  const float* Ws2  = (const float*)d_in[16];
  const float* bs2  = (const float*)d_in[17];
  const float* Wf1  = (const float*)d_in[18];
  const float* bf1  = (const float*)d_in[19];
  const float* Wfa  = (const float*)d_in[20];
  const float* bfa  = (const float*)d_in[21];
  const float* Wfb  = (const float*)d_in[22];
  const float* bfb  = (const float*)d_in[23];

  float* ws = (float*)d_ws;
  float* wrm1 = ws;
  float* wrm2 = wrm1 + 65536;
  float* hp1  = wrm2 + 65536;
  float* hp2  = hp1 + (size_t)N_P * 256;
  float* es1v = hp2 + (size_t)N_ALLC * 256;
  float* ed1v = es1v + 8 * N_P;
  float* es2v = ed1v + 8 * N_P;
  float* ed2v = es2v + 8 * N_ALLC;
  float* h1wp = ed2v + 8 * N_ALLC;
  float* h2w  = h1wp + (size_t)N_ALLC * 256;
  float* o12  = h2w + N_W * 32;
  float* tbuf = o12 + (size_t)BQ * 256;

  float* out = (float*)d_out;
  float* out_o1n = out;                                   // [B][64]
  float* out_o2n = out + (size_t)BQ * 64;                 // [B][64]
  float* out_xt  = out + (size_t)BQ * 128;                // [B][5]
  float* out_app = out_xt + (size_t)BQ * 5;               // [8][2048][2048]
  float* out_awp = out_app + (size_t)8 * N_P * N_P;       // [8][2137][2137]
  float* out_x   = out_awp + (size_t)8 * N_ALLC * N_ALLC; // [B][256]

  repack_w<<<256, 256, 0, stream>>>(w1, wrm1);
  repack_w<<<256, 256, 0, stream>>>(w2, wrm2);
  copy_word<<<89, 256, 0, stream>>>(wf, h1wp);

  // hp1 = pern_feature @ W1rm  (2048,256,256)
  gemm_f32<<<dim3(32, 4), 256, 0, stream>>>(pf, 256, wrm1, 256, hp1, 256, nullptr, N_P, 256, 256, 0);
  esrc_edst<<<(N_P * 8 + 255) / 256, 256, 0, stream>>>(hp1, as1, ad1, es1v, ed1v, N_P);
  gat_attn1<<<N_P, 256, 0, stream>>>(es1v, ed1v, adj1, out_app);
  pv_gemm1<<<dim3(N_P / 64, 8), 256, 0, stream>>>(out_app, hp1, b1, h1wp);

  // hp2 = h1wp @ W2rm  (2137,256,256)
  gemm_f32<<<dim3(34, 4), 256, 0, stream>>>(h1wp, 256, wrm2, 256, hp2, 256, nullptr, N_ALLC, 256, 256, 0);
  esrc_edst<<<(N_ALLC * 8 + 255) / 256, 256, 0, stream>>>(hp2, as2, ad2, es2v, ed2v, N_ALLC);
  gat_attn2<<<N_ALLC, 256, 0, stream>>>(hp2, es2v, ed2v, adj2, b2, out_awp, h2w);

  xnorm_kernel<<<BQ / 4, 256, 0, stream>>>(uwa, h2w, out_x);

  // o1 = x @ W_s1 + b_s1 -> o12[:, :128]
  gemm_f32<<<dim3(BQ / 64, 2), 256, 0, stream>>>(out_x, 256, Ws1, 128, o12, 256, bs1, BQ, 128, 256, 0);
  // o2 = sent @ W_s2 + b_s2 -> o12[:, 128:]
  gemm_f32<<<dim3(BQ / 64, 2), 256, 0, stream>>>(sent, E2C, Ws2, 128, o12 + 128, 256, bs2, BQ, 128, E2C, 0);
  // output1_new = o1 @ W_f1 + b_f1
  gemm_f32<<<dim3(BQ / 64, 1), 256, 0, stream>>>(o12, 256, Wf1, 64, out_o1n, 64, bf1, BQ, 64, 128, 0);
  // output2_new = o2 @ W_f1 + b_f1
  gemm_f32<<<dim3(BQ / 64, 1), 256, 0, stream>>>(o12 + 128, 256, Wf1, 64, out_o2n, 64, bf1, BQ, 64, 128, 0);
  // t = relu(cat(o1,o2) @ W_fa + b_fa)
  gemm_f32<<<dim3(BQ / 64, 2), 256, 0, stream>>>(o12, 256, Wfa, 128, tbuf, 128, bfa, BQ, 128, 256, 1);
  // xtemp = t @ W_fb + b_fb
  final5<<<BQ / 32, 256, 0, stream>>>(tbuf, Wfb, bfb, out_xt);
}

// Round 2
// 960.709 us; speedup vs baseline: 1.3404x; 1.3404x over previous
//
#include <hip/hip_runtime.h>
#include <cstdint>
#include <cstddef>

#define N_P 2048
#define N_W 89
#define N_ALLC 2137
#define BQ 16384
#define E2C 768

// ---------------- reduce helpers ----------------
__device__ __forceinline__ float waveMax(float v){
#pragma unroll
  for (int o = 32; o > 0; o >>= 1) v = fmaxf(v, __shfl_down(v, o, 64));
  return v;
}
__device__ __forceinline__ float waveSum(float v){
#pragma unroll
  for (int o = 32; o > 0; o >>= 1) v += __shfl_down(v, o, 64);
  return v;
}

// ---------------- repack w (8,256,32) -> row-major (256,256) ----------------
__global__ __launch_bounds__(256) void repack_w(const float* __restrict__ w,
                                                float* __restrict__ wrm) {
  int idx = blockIdx.x * 256 + threadIdx.x;           // < 65536
  int f = idx >> 8, c = idx & 255;
  int h = c >> 5, o = c & 31;
  wrm[idx] = w[h * 8192 + f * 32 + o];
}

// ---------------- copy word_feature into h1wp rows 0..88 ----------------
__global__ __launch_bounds__(256) void copy_word(const float* __restrict__ wf,
                                                 float* __restrict__ h1wp) {
  int idx = blockIdx.x * 256 + threadIdx.x;
  if (idx < N_W * 256) h1wp[idx] = wf[idx];
}

// ---------------- generic f32 GEMM: C[M,N] = A[M,K]@B[K,N] + bias ----------------
__global__ __launch_bounds__(256) void gemm_f32(
    const float* __restrict__ A, int lda,
    const float* __restrict__ B, int ldb,
    float* __restrict__ C, int ldc,
    const float* __restrict__ bias,
    int M, int N, int K, int relu)
{
  __shared__ __align__(16) float As[16][68];
  __shared__ __align__(16) float Bs[16][68];
  int t = threadIdx.x;
  int m0 = blockIdx.x * 64, n0 = blockIdx.y * 64;
  int tm = t >> 4, tn = t & 15;
  int ar = t >> 2, ak = (t & 3) * 4;
  int bk = t >> 4, bn = (t & 15) * 4;
  float acc[4][4] = {};
  for (int k0 = 0; k0 < K; k0 += 16) {
    float4 av = {0.f, 0.f, 0.f, 0.f};
    int arow = m0 + ar;
    if (arow < M) av = *(const float4*)(A + (size_t)arow * lda + k0 + ak);
    As[ak][ar] = av.x; As[ak + 1][ar] = av.y; As[ak + 2][ar] = av.z; As[ak + 3][ar] = av.w;
    *(float4*)&Bs[bk][bn] = *(const float4*)(B + (size_t)(k0 + bk) * ldb + n0 + bn);
    __syncthreads();
#pragma unroll
    for (int kk = 0; kk < 16; ++kk) {
      float4 a4 = *(const float4*)&As[kk][tm * 4];
      float4 b4 = *(const float4*)&Bs[kk][tn * 4];
      float a[4] = {a4.x, a4.y, a4.z, a4.w};
      float b[4] = {b4.x, b4.y, b4.z, b4.w};
#pragma unroll
      for (int i = 0; i < 4; ++i)
#pragma unroll
        for (int j = 0; j < 4; ++j) acc[i][j] += a[i] * b[j];
    }
    __syncthreads();
  }
  float4 bb = {0.f, 0.f, 0.f, 0.f};
  if (bias) bb = *(const float4*)(bias + n0 + tn * 4);
  float bbv[4] = {bb.x, bb.y, bb.z, bb.w};
#pragma unroll
  for (int i = 0; i < 4; ++i) {
    int row = m0 + tm * 4 + i;
    if (row < M) {
      float4 v;
      float r0 = acc[i][0] + bbv[0], r1 = acc[i][1] + bbv[1];
      float r2 = acc[i][2] + bbv[2], r3 = acc[i][3] + bbv[3];
      if (relu) { r0 = fmaxf(r0, 0.f); r1 = fmaxf(r1, 0.f); r2 = fmaxf(r2, 0.f); r3 = fmaxf(r3, 0.f); }
      v.x = r0; v.y = r1; v.z = r2; v.w = r3;
      *(float4*)(C + (size_t)row * ldc + n0 + tn * 4) = v;
    }
  }
}

// ---------------- e_src / e_dst ----------------
__global__ __launch_bounds__(256) void esrc_edst(
    const float* __restrict__ hp,
    const float* __restrict__ a_src,
    const float* __restrict__ a_dst,
    float* __restrict__ es, float* __restrict__ ed, int N)
{
  __shared__ float sa[256], sd[256];
  int t = threadIdx.x;
  sa[t] = a_src[t]; sd[t] = a_dst[t];
  __syncthreads();
  int idx = blockIdx.x * 256 + t;
  if (idx >= N * 8) return;
  int n = idx >> 3, h = idx & 7;
  const float* hpp = hp + (size_t)n * 256 + h * 32;
  const float* ap = sa + h * 32;
  const float* dp = sd + h * 32;
  float s = 0.f, d = 0.f;
#pragma unroll
  for (int o = 0; o < 32; ++o) { float v = hpp[o]; s += v * ap[o]; d += v * dp[o]; }
  es[h * N + n] = s; ed[h * N + n] = d;
}

// ---------------- attention softmax: one block per (head,row), vals in regs ----------------
__global__ __launch_bounds__(256) void attn_softmax(
    const float* __restrict__ es, const float* __restrict__ ed,   // [8][N]
    const int* __restrict__ adj,                                  // [N][N]
    float* __restrict__ attn,                                     // [8][N][N]
    int N)
{
  int h = blockIdx.x, n = blockIdx.y;
  int t = threadIdx.x, lane = t & 63, wid = t >> 6;
  __shared__ float red[4];
  float esv = es[h * N + n];
  const float* edh = ed + (size_t)h * N;
  const int* arow = adj + (size_t)n * N;
  float v[9];
  float lmax = -3e38f;
#pragma unroll
  for (int i = 0; i < 9; ++i) {
    int m = i * 256 + t;
    float x = -3e38f;
    if (m < N) {
      float e = esv + edh[m];
      e = (e >= 0.f) ? e : 0.2f * e;
      x = (arow[m] > 0) ? e : -1e9f;
    }
    v[i] = x; lmax = fmaxf(lmax, x);
  }
  lmax = waveMax(lmax);
  if (lane == 0) red[wid] = lmax;
  __syncthreads();
  float gmax = fmaxf(fmaxf(red[0], red[1]), fmaxf(red[2], red[3]));
  __syncthreads();
  float lsum = 0.f;
#pragma unroll
  for (int i = 0; i < 9; ++i) {
    int m = i * 256 + t;
    if (m < N) { float p = __expf(v[i] - gmax); v[i] = p; lsum += p; }
  }
  lsum = waveSum(lsum);
  if (lane == 0) red[wid] = lsum;
  __syncthreads();
  float inv = 1.f / (red[0] + red[1] + red[2] + red[3]);
  float* out = attn + ((size_t)h * N + n) * N;
#pragma unroll
  for (int i = 0; i < 9; ++i) {
    int m = i * 256 + t;
    if (m < N) out[m] = v[i] * inv;
  }
}

// ---------------- PV GEMM for GAT1: h1wp[89+m] = elu(attn@hp + bias) ----------------
__global__ __launch_bounds__(256) void pv_gemm1(
    const float* __restrict__ attn,   // [8][2048][2048] (normalized)
    const float* __restrict__ hp,     // [2048][256]
    const float* __restrict__ bias,   // [32]
    float* __restrict__ h1wp)         // [2137][256]
{
  __shared__ __align__(16) float As[32][66];
  __shared__ __align__(16) float Bs[32][36];
  int t = threadIdx.x;
  int h = blockIdx.y;
  int m0 = blockIdx.x * 64;
  int tm = t >> 3, tn = t & 7;
  float acc[2][4] = {};
  const float* abase = attn + ((size_t)h * N_P + m0) * N_P;
  for (int k0 = 0; k0 < N_P; k0 += 32) {
    for (int idx = t; idx < 64 * 32; idx += 256) {
      int r = idx >> 5, c = idx & 31;
      As[c][r] = abase[(size_t)r * N_P + k0 + c];
    }
    for (int idx = t; idx < 32 * 32; idx += 256) {
      int r = idx >> 5, c = idx & 31;
      Bs[r][c] = hp[(size_t)(k0 + r) * 256 + h * 32 + c];
    }
    __syncthreads();
#pragma unroll
    for (int kk = 0; kk < 32; ++kk) {
      float2 a2 = *(const float2*)&As[kk][tm * 2];
      float4 b4 = *(const float4*)&Bs[kk][tn * 4];
      acc[0][0] += a2.x * b4.x; acc[0][1] += a2.x * b4.y; acc[0][2] += a2.x * b4.z; acc[0][3] += a2.x * b4.w;
      acc[1][0] += a2.y * b4.x; acc[1][1] += a2.y * b4.y; acc[1][2] += a2.y * b4.z; acc[1][3] += a2.y * b4.w;
    }
    __syncthreads();
  }
  float4 bv = *(const float4*)(bias + tn * 4);
  float bvv[4] = {bv.x, bv.y, bv.z, bv.w};
#pragma unroll
  for (int i = 0; i < 2; ++i) {
    int row = m0 + tm * 2 + i;
    float4 o;
    float r0 = acc[i][0] + bvv[0], r1 = acc[i][1] + bvv[1];
    float r2 = acc[i][2] + bvv[2], r3 = acc[i][3] + bvv[3];
    o.x = (r0 > 0.f) ? r0 : expm1f(r0);
    o.y = (r1 > 0.f) ? r1 : expm1f(r1);
    o.z = (r2 > 0.f) ? r2 : expm1f(r2);
    o.w = (r3 > 0.f) ? r3 : expm1f(r3);
    *(float4*)(h1wp + (size_t)(N_W + row) * 256 + h * 32 + tn * 4) = o;
  }
}

// ---------------- h2w init with bias ----------------
__global__ __launch_bounds__(256) void h2w_init(const float* __restrict__ bias,
                                                float* __restrict__ h2w) {
  int idx = blockIdx.x * 256 + threadIdx.x;
  if (idx < N_W * 32) h2w[idx] = bias[idx & 31];
}

// ---------------- PV for GAT2 word rows: h2w += mean_h(attn@hp) ----------------
__global__ __launch_bounds__(256) void pv2(
    const float* __restrict__ attn,   // [8][2137][2137] (normalized)
    const float* __restrict__ hp,     // [2137][256]
    float* __restrict__ h2w)          // [89][32]
{
  int n = blockIdx.x, h = blockIdx.y;
  int t = threadIdx.x, g = t >> 5, o = t & 31;
  const float* arow = attn + ((size_t)h * N_ALLC + n) * N_ALLC;
  float acc = 0.f;
  for (int m = g; m < N_ALLC; m += 8) acc += arow[m] * hp[(size_t)m * 256 + h * 32 + o];
  __shared__ float pv[8][33];
  pv[g][o] = acc;
  __syncthreads();
  if (t < 32) {
    float s = 0.f;
#pragma unroll
    for (int gg = 0; gg < 8; ++gg) s += pv[gg][t];
    atomicAdd(&h2w[n * 32 + t], s * 0.125f);
  }
}

// ---------------- x: head matmul + concat + row-normalize ----------------
__global__ __launch_bounds__(256) void xnorm_kernel(
    const float* __restrict__ uwa,   // [B][313]
    const float* __restrict__ h2w,   // [89][32]
    float* __restrict__ xout)        // [B][256]
{
  __shared__ float urow[4][320];
  __shared__ float xh[4][33];
  __shared__ float inv[4];
  int t = threadIdx.x;
  int b0 = blockIdx.x * 4;
  for (int idx = t; idx < 4 * 313; idx += 256) {
    int r = idx / 313, j = idx - r * 313;
    urow[r][j] = uwa[(size_t)(b0 + r) * 313 + j];
  }
  __syncthreads();
  if (t < 128) {
    int r = t >> 5, o = t & 31;
    float s = 0.f;
    for (int i = 0; i < N_W; ++i) s += urow[r][i] * h2w[i * 32 + o];
    xh[r][o] = s;
  }
  __syncthreads();
  int lane = t & 63, w = t >> 6;
  float ls = 0.f;
  for (int c = lane; c < 256; c += 64) {
    float v = (c < 32) ? xh[w][c] : urow[w][89 + c - 32];
    ls += v;
  }
  ls = waveSum(ls);
  if (lane == 0) inv[w] = 1.f / ls;
  __syncthreads();
  for (int idx = t; idx < 1024; idx += 256) {
    int r = idx >> 8, c = idx & 255;
    float v = (c < 32) ? xh[r][c] : urow[r][89 + c - 32];
    xout[(size_t)(b0 + r) * 256 + c] = v * inv[r];
  }
}

// ---------------- final tiny GEMM: xtemp = t[B,128] @ Wfb[128,5] + bfb ----------------
__global__ __launch_bounds__(256) void final5(
    const float* __restrict__ tb,   // [B][128]
    const float* __restrict__ Wfb,  // [128][5]
    const float* __restrict__ bfb,  // [5]
    float* __restrict__ out)        // [B][5]
{
  __shared__ float tt[32][129];
  __shared__ float wfb[5][128];
  int t = threadIdx.x;
  int b0 = blockIdx.x * 32;
  for (int idx = t; idx < 32 * 128; idx += 256) {
    int r = idx >> 7, c = idx & 127;
    tt[r][c] = tb[(size_t)(b0 + r) * 128 + c];
  }
  for (int idx = t; idx < 640; idx += 256) {
    int q = idx >> 7, j = idx & 127;
    wfb[q][j] = Wfb[j * 5 + q];
  }
  __syncthreads();
  if (t < 160) {
    int q = t >> 5, r = t & 31;
    float s = bfb[q];
    const float* wq = wfb[q];
    for (int j = 0; j < 128; ++j) s += tt[r][j] * wq[j];
    out[(size_t)(b0 + r) * 5 + q] = s;
  }
}

extern "C" void kernel_launch(void* const* d_in, const int* in_sizes, int n_in,
                              void* d_out, int out_size, void* d_ws, size_t ws_size,
                              hipStream_t stream)
{
  const float* pf   = (const float*)d_in[0];
  const float* wf   = (const float*)d_in[1];
  const int*   adj1 = (const int*)d_in[2];
  const int*   adj2 = (const int*)d_in[3];
  const float* uwa  = (const float*)d_in[4];
  const float* sent = (const float*)d_in[5];
  const float* w1   = (const float*)d_in[6];
  const float* as1  = (const float*)d_in[7];
  const float* ad1  = (const float*)d_in[8];
  const float* b1   = (const float*)d_in[9];
  const float* w2   = (const float*)d_in[10];
  const float* as2  = (const float*)d_in[11];
  const float* ad2  = (const float*)d_in[12];
  const float* b2   = (const float*)d_in[13];
  const float* Ws1  = (const float*)d_in[14];
  const float* bs1  = (const float*)d_in[15];
  const float* Ws2  = (const float*)d_in[16];
  const float* bs2  = (const float*)d_in[17];
  const float* Wf1  = (const float*)d_in[18];
  const float* bf1  = (const float*)d_in[19];
  const float* Wfa  = (const float*)d_in[20];
  const float* bfa  = (const float*)d_in[21];
  const float* Wfb  = (const float*)d_in[22];
  const float* bfb  = (const float*)d_in[23];

  float* ws = (float*)d_ws;
  float* wrm1 = ws;
  float* wrm2 = wrm1 + 65536;
  float* hp1  = wrm2 + 65536;
  float* hp2  = hp1 + (size_t)N_P * 256;
  float* es1v = hp2 + (size_t)N_ALLC * 256;
  float* ed1v = es1v + 8 * N_P;
  float* es2v = ed1v + 8 * N_P;
  float* ed2v = es2v + 8 * N_ALLC;
  float* h1wp = ed2v + 8 * N_ALLC;
  float* h2w  = h1wp + (size_t)N_ALLC * 256;
  float* o12  = h2w + N_W * 32;
  float* tbuf = o12 + (size_t)BQ * 256;

  float* out = (float*)d_out;
  float* out_o1n = out;                                   // [B][64]
  float* out_o2n = out + (size_t)BQ * 64;                 // [B][64]
  float* out_xt  = out + (size_t)BQ * 128;                // [B][5]
  float* out_app = out_xt + (size_t)BQ * 5;               // [8][2048][2048]
  float* out_awp = out_app + (size_t)8 * N_P * N_P;       // [8][2137][2137]
  float* out_x   = out_awp + (size_t)8 * N_ALLC * N_ALLC; // [B][256]

  repack_w<<<256, 256, 0, stream>>>(w1, wrm1);
  repack_w<<<256, 256, 0, stream>>>(w2, wrm2);
  copy_word<<<89, 256, 0, stream>>>(wf, h1wp);

  // hp1 = pern_feature @ W1rm  (2048,256,256)
  gemm_f32<<<dim3(32, 4), 256, 0, stream>>>(pf, 256, wrm1, 256, hp1, 256, nullptr, N_P, 256, 256, 0);
  esrc_edst<<<(N_P * 8 + 255) / 256, 256, 0, stream>>>(hp1, as1, ad1, es1v, ed1v, N_P);
  attn_softmax<<<dim3(8, N_P), 256, 0, stream>>>(es1v, ed1v, adj1, out_app, N_P);
  pv_gemm1<<<dim3(N_P / 64, 8), 256, 0, stream>>>(out_app, hp1, b1, h1wp);

  // hp2 = h1wp @ W2rm  (2137,256,256)
  gemm_f32<<<dim3(34, 4), 256, 0, stream>>>(h1wp, 256, wrm2, 256, hp2, 256, nullptr, N_ALLC, 256, 256, 0);
  esrc_edst<<<(N_ALLC * 8 + 255) / 256, 256, 0, stream>>>(hp2, as2, ad2, es2v, ed2v, N_ALLC);
  attn_softmax<<<dim3(8, N_ALLC), 256, 0, stream>>>(es2v, ed2v, adj2, out_awp, N_ALLC);

  h2w_init<<<(N_W * 32 + 255) / 256, 256, 0, stream>>>(b2, h2w);
  pv2<<<dim3(N_W, 8), 256, 0, stream>>>(out_awp, hp2, h2w);

  xnorm_kernel<<<BQ / 4, 256, 0, stream>>>(uwa, h2w, out_x);

  // o1 = x @ W_s1 + b_s1 -> o12[:, :128]
  gemm_f32<<<dim3(BQ / 64, 2), 256, 0, stream>>>(out_x, 256, Ws1, 128, o12, 256, bs1, BQ, 128, 256, 0);
  // o2 = sent @ W_s2 + b_s2 -> o12[:, 128:]
  gemm_f32<<<dim3(BQ / 64, 2), 256, 0, stream>>>(sent, E2C, Ws2, 128, o12 + 128, 256, bs2, BQ, 128, E2C, 0);
  // output1_new = o1 @ W_f1 + b_f1
  gemm_f32<<<dim3(BQ / 64, 1), 256, 0, stream>>>(o12, 256, Wf1, 64, out_o1n, 64, bf1, BQ, 64, 128, 0);
  // output2_new = o2 @ W_f1 + b_f1
  gemm_f32<<<dim3(BQ / 64, 1), 256, 0, stream>>>(o12 + 128, 256, Wf1, 64, out_o2n, 64, bf1, BQ, 64, 128, 0);
  // t = relu(cat(o1,o2) @ W_fa + b_fa)
  gemm_f32<<<dim3(BQ / 64, 2), 256, 0, stream>>>(o12, 256, Wfa, 128, tbuf, 128, bfa, BQ, 128, 256, 1);
  // xtemp = t @ W_fb + b_fb
  final5<<<BQ / 32, 256, 0, stream>>>(tbuf, Wfb, bfb, out_xt);
}

// Round 3
// 757.779 us; speedup vs baseline: 1.6993x; 1.2678x over previous
//
#include <hip/hip_runtime.h>
#include <cstdint>
#include <cstddef>

#define N_P 2048
#define N_W 89
#define N_ALLC 2137
#define BQ 16384
#define E2C 768

typedef __attribute__((ext_vector_type(8))) short short8;
typedef __attribute__((ext_vector_type(4))) float float4v;

// ---------------- helpers ----------------
__device__ __forceinline__ float waveMax(float v){
#pragma unroll
  for (int o = 32; o > 0; o >>= 1) v = fmaxf(v, __shfl_down(v, o, 64));
  return v;
}
__device__ __forceinline__ float waveSum(float v){
#pragma unroll
  for (int o = 32; o > 0; o >>= 1) v += __shfl_down(v, o, 64);
  return v;
}
__device__ __forceinline__ unsigned short f2bf(float f){
  union { float f; unsigned int u; } v; v.f = f;
  unsigned int u = v.u;
  unsigned int r = (u + 0x7FFFu + ((u >> 16) & 1u)) >> 16;
  return (unsigned short)r;
}

// ---------------- repack w (8,256,32) -> row-major (256,256) ----------------
__global__ __launch_bounds__(256) void repack_w(const float* __restrict__ w,
                                                float* __restrict__ wrm) {
  int idx = blockIdx.x * 256 + threadIdx.x;
  int f = idx >> 8, c = idx & 255;
  int h = c >> 5, o = c & 31;
  wrm[idx] = w[h * 8192 + f * 32 + o];
}

// ---------------- repack weight W[K][N] f32 -> bf16 MFMA B-fragment layout ----------------
// out[((kb*4+q)*N + n)*8 + j] = bf16(W[(kb*32+q*8+j)*N + n])
__global__ __launch_bounds__(256) void repack_wpk(const float* __restrict__ W,
                                                  unsigned short* __restrict__ out,
                                                  int K, int N) {
  int idx = blockIdx.x * 256 + threadIdx.x;
  if (idx >= K * N) return;
  int k = idx / N, n = idx - k * N;
  int kb = k >> 5, q = (k >> 3) & 3, j = k & 7;
  out[((size_t)(kb * 4 + q) * N + n) * 8 + j] = f2bf(W[idx]);
}

// ---------------- copy word_feature into h1wp rows 0..88 ----------------
__global__ __launch_bounds__(256) void copy_word(const float* __restrict__ wf,
                                                 float* __restrict__ h1wp) {
  int idx = blockIdx.x * 256 + threadIdx.x;
  if (idx < N_W * 256) h1wp[idx] = wf[idx];
}

// ---------------- generic f32 GEMM (used only for hp1/hp2, small) ----------------
__global__ __launch_bounds__(256) void gemm_f32(
    const float* __restrict__ A, int lda,
    const float* __restrict__ B, int ldb,
    float* __restrict__ C, int ldc,
    const float* __restrict__ bias,
    int M, int N, int K, int relu)
{
  __shared__ __align__(16) float As[16][68];
  __shared__ __align__(16) float Bs[16][68];
  int t = threadIdx.x;
  int m0 = blockIdx.x * 64, n0 = blockIdx.y * 64;
  int tm = t >> 4, tn = t & 15;
  int ar = t >> 2, ak = (t & 3) * 4;
  int bk = t >> 4, bn = (t & 15) * 4;
  float acc[4][4] = {};
  for (int k0 = 0; k0 < K; k0 += 16) {
    float4 av = {0.f, 0.f, 0.f, 0.f};
    int arow = m0 + ar;
    if (arow < M) av = *(const float4*)(A + (size_t)arow * lda + k0 + ak);
    As[ak][ar] = av.x; As[ak + 1][ar] = av.y; As[ak + 2][ar] = av.z; As[ak + 3][ar] = av.w;
    *(float4*)&Bs[bk][bn] = *(const float4*)(B + (size_t)(k0 + bk) * ldb + n0 + bn);
    __syncthreads();
#pragma unroll
    for (int kk = 0; kk < 16; ++kk) {
      float4 a4 = *(const float4*)&As[kk][tm * 4];
      float4 b4 = *(const float4*)&Bs[kk][tn * 4];
      float a[4] = {a4.x, a4.y, a4.z, a4.w};
      float b[4] = {b4.x, b4.y, b4.z, b4.w};
#pragma unroll
      for (int i = 0; i < 4; ++i)
#pragma unroll
        for (int j = 0; j < 4; ++j) acc[i][j] += a[i] * b[j];
    }
    __syncthreads();
  }
#pragma unroll
  for (int i = 0; i < 4; ++i) {
    int row = m0 + tm * 4 + i;
    if (row < M) {
      float4 v;
      v.x = acc[i][0]; v.y = acc[i][1]; v.z = acc[i][2]; v.w = acc[i][3];
      *(float4*)(C + (size_t)row * ldc + n0 + tn * 4) = v;
    }
  }
}

// ---------------- MFMA bf16 GEMM: C[M, n0+64) = A[M,K](f32) @ Wpk + bias ----------------
// A converted to bf16 in-register. Weights pre-repacked (repack_wpk). M%64==0.
__global__ __launch_bounds__(256) void gemm_mfma(
    const float* __restrict__ A, int lda,
    const unsigned short* __restrict__ Wpk, int N,
    const float* __restrict__ bias,
    float* __restrict__ C, int ldc,
    int K, int relu)
{
  int t = threadIdx.x;
  int w = t >> 6, lane = t & 63;
  int col = lane & 15, quad = lane >> 4;
  int rowA = blockIdx.x * 64 + w * 16 + col;
  int n0 = blockIdx.y * 64;
  const float* arow = A + (size_t)rowA * lda;
  float4v acc[4];
#pragma unroll
  for (int nt = 0; nt < 4; ++nt) acc[nt] = (float4v){0.f, 0.f, 0.f, 0.f};
  for (int k0 = 0; k0 < K; k0 += 32) {
    const float* ap = arow + k0 + quad * 8;
    float4 f0 = *(const float4*)(ap);
    float4 f1 = *(const float4*)(ap + 4);
    short8 a;
    a[0] = (short)f2bf(f0.x); a[1] = (short)f2bf(f0.y);
    a[2] = (short)f2bf(f0.z); a[3] = (short)f2bf(f0.w);
    a[4] = (short)f2bf(f1.x); a[5] = (short)f2bf(f1.y);
    a[6] = (short)f2bf(f1.z); a[7] = (short)f2bf(f1.w);
    const unsigned short* wb = Wpk + ((size_t)((k0 >> 5) * 4 + quad) * N + n0 + col) * 8;
#pragma unroll
    for (int nt = 0; nt < 4; ++nt) {
      short8 b = *(const short8*)(wb + (size_t)nt * 16 * 8);
      acc[nt] = __builtin_amdgcn_mfma_f32_16x16x32_bf16(a, b, acc[nt], 0, 0, 0);
    }
  }
  int rbase = blockIdx.x * 64 + w * 16 + quad * 4;
#pragma unroll
  for (int nt = 0; nt < 4; ++nt) {
    int c = n0 + nt * 16 + col;
    float bv = bias[c];
#pragma unroll
    for (int r = 0; r < 4; ++r) {
      float v = acc[nt][r] + bv;
      if (relu) v = fmaxf(v, 0.f);
      C[(size_t)(rbase + r) * ldc + c] = v;
    }
  }
}

// ---------------- e_src / e_dst ----------------
__global__ __launch_bounds__(256) void esrc_edst(
    const float* __restrict__ hp,
    const float* __restrict__ a_src,
    const float* __restrict__ a_dst,
    float* __restrict__ es, float* __restrict__ ed, int N)
{
  __shared__ float sa[256], sd[256];
  int t = threadIdx.x;
  sa[t] = a_src[t]; sd[t] = a_dst[t];
  __syncthreads();
  int idx = blockIdx.x * 256 + t;
  if (idx >= N * 8) return;
  int n = idx >> 3, h = idx & 7;
  const float* hpp = hp + (size_t)n * 256 + h * 32;
  const float* ap = sa + h * 32;
  const float* dp = sd + h * 32;
  float s = 0.f, d = 0.f;
#pragma unroll
  for (int o = 0; o < 32; ++o) { float v = hpp[o]; s += v * ap[o]; d += v * dp[o]; }
  es[h * N + n] = s; ed[h * N + n] = d;
}

// ---------------- attention softmax: one block per (head,row) ----------------
__global__ __launch_bounds__(256) void attn_softmax(
    const float* __restrict__ es, const float* __restrict__ ed,
    const int* __restrict__ adj,
    float* __restrict__ attn,
    int N)
{
  int h = blockIdx.x, n = blockIdx.y;
  int t = threadIdx.x, lane = t & 63, wid = t >> 6;
  __shared__ float red[4];
  float esv = es[h * N + n];
  const float* edh = ed + (size_t)h * N;
  const int* arow = adj + (size_t)n * N;
  float v[9];
  float lmax = -3e38f;
#pragma unroll
  for (int i = 0; i < 9; ++i) {
    int m = i * 256 + t;
    float x = -3e38f;
    if (m < N) {
      float e = esv + edh[m];
      e = (e >= 0.f) ? e : 0.2f * e;
      x = (arow[m] > 0) ? e : -1e9f;
    }
    v[i] = x; lmax = fmaxf(lmax, x);
  }
  lmax = waveMax(lmax);
  if (lane == 0) red[wid] = lmax;
  __syncthreads();
  float gmax = fmaxf(fmaxf(red[0], red[1]), fmaxf(red[2], red[3]));
  __syncthreads();
  float lsum = 0.f;
#pragma unroll
  for (int i = 0; i < 9; ++i) {
    int m = i * 256 + t;
    if (m < N) { float p = __expf(v[i] - gmax); v[i] = p; lsum += p; }
  }
  lsum = waveSum(lsum);
  if (lane == 0) red[wid] = lsum;
  __syncthreads();
  float inv = 1.f / (red[0] + red[1] + red[2] + red[3]);
  float* out = attn + ((size_t)h * N + n) * N;
#pragma unroll
  for (int i = 0; i < 9; ++i) {
    int m = i * 256 + t;
    if (m < N) out[m] = v[i] * inv;
  }
}

// ---------------- PV1 partial: parts[ks] = attn[h, m0:m0+128, ks*512:+512] @ hp ----------------
// grid (16, 8, 4), block 256. Thread: 4 rows x 4 cols.
__global__ __launch_bounds__(256) void pv1_partial(
    const float* __restrict__ attn,   // [8][2048][2048]
    const float* __restrict__ hp,     // [2048][256]
    float* __restrict__ parts)        // [4][2048][256]
{
  __shared__ __align__(16) float As[128][68];
  __shared__ __align__(16) float Bs[64][36];
  int t = threadIdx.x;
  int m0 = blockIdx.x * 128;
  int h  = blockIdx.y;
  int ks = blockIdx.z;
  int ro = t >> 3;   // 0..31 -> rows 4ro..4ro+3
  int co = t & 7;    // cols 4co..4co+3
  float acc[4][4] = {};
  const float* abase = attn + ((size_t)h * N_P + m0) * N_P;
  for (int k0 = ks * 512; k0 < ks * 512 + 512; k0 += 64) {
#pragma unroll
    for (int i = 0; i < 8; ++i) {
      int idx = t + i * 256;
      int r = idx >> 4, c4 = idx & 15;
      float4 v = *(const float4*)(abase + (size_t)r * N_P + k0 + c4 * 4);
      *(float4*)&As[r][c4 * 4] = v;
    }
#pragma unroll
    for (int i = 0; i < 2; ++i) {
      int idx = t + i * 256;
      int r = idx >> 3, c4 = idx & 7;
      float4 v = *(const float4*)(hp + (size_t)(k0 + r) * 256 + h * 32 + c4 * 4);
      *(float4*)&Bs[r][c4 * 4] = v;
    }
    __syncthreads();
#pragma unroll 16
    for (int kk = 0; kk < 64; ++kk) {
      float4 b4 = *(const float4*)&Bs[kk][co * 4];
#pragma unroll
      for (int i = 0; i < 4; ++i) {
        float a = As[ro * 4 + i][kk];
        acc[i][0] += a * b4.x; acc[i][1] += a * b4.y;
        acc[i][2] += a * b4.z; acc[i][3] += a * b4.w;
      }
    }
    __syncthreads();
  }
  float* p = parts + (size_t)ks * (N_P * 256);
#pragma unroll
  for (int i = 0; i < 4; ++i) {
    int row = m0 + ro * 4 + i;
    float4 v; v.x = acc[i][0]; v.y = acc[i][1]; v.z = acc[i][2]; v.w = acc[i][3];
    *(float4*)&p[(size_t)row * 256 + h * 32 + co * 4] = v;
  }
}

// ---------------- PV1 epilogue: sum 4 partials + bias, elu, write h1wp rows 89.. ----------------
__global__ __launch_bounds__(256) void pv1_epilogue(
    const float* __restrict__ parts,
    const float* __restrict__ bias,
    float* __restrict__ h1wp)
{
  int idx = blockIdx.x * 256 + threadIdx.x;   // over 2048*256
  float s = parts[idx] + parts[idx + N_P * 256] + parts[idx + 2 * N_P * 256] + parts[idx + 3 * N_P * 256];
  s += bias[idx & 31];
  h1wp[(size_t)N_W * 256 + idx] = (s > 0.f) ? s : expm1f(s);
}

// ---------------- h2w init with bias ----------------
__global__ __launch_bounds__(256) void h2w_init(const float* __restrict__ bias,
                                                float* __restrict__ h2w) {
  int idx = blockIdx.x * 256 + threadIdx.x;
  if (idx < N_W * 32) h2w[idx] = bias[idx & 31];
}

// ---------------- PV for GAT2 word rows ----------------
__global__ __launch_bounds__(256) void pv2(
    const float* __restrict__ attn,
    const float* __restrict__ hp,
    float* __restrict__ h2w)
{
  int n = blockIdx.x, h = blockIdx.y;
  int t = threadIdx.x, g = t >> 5, o = t & 31;
  const float* arow = attn + ((size_t)h * N_ALLC + n) * N_ALLC;
  float acc = 0.f;
  for (int m = g; m < N_ALLC; m += 8) acc += arow[m] * hp[(size_t)m * 256 + h * 32 + o];
  __shared__ float pv[8][33];
  pv[g][o] = acc;
  __syncthreads();
  if (t < 32) {
    float s = 0.f;
#pragma unroll
    for (int gg = 0; gg < 8; ++gg) s += pv[gg][t];
    atomicAdd(&h2w[n * 32 + t], s * 0.125f);
  }
}

// ---------------- x: head matmul + concat + row-normalize ----------------
__global__ __launch_bounds__(256) void xnorm_kernel(
    const float* __restrict__ uwa,
    const float* __restrict__ h2w,
    float* __restrict__ xout)
{
  __shared__ float urow[4][320];
  __shared__ float xh[4][33];
  __shared__ float inv[4];
  int t = threadIdx.x;
  int b0 = blockIdx.x * 4;
  for (int idx = t; idx < 4 * 313; idx += 256) {
    int r = idx / 313, j = idx - r * 313;
    urow[r][j] = uwa[(size_t)(b0 + r) * 313 + j];
  }
  __syncthreads();
  if (t < 128) {
    int r = t >> 5, o = t & 31;
    float s = 0.f;
    for (int i = 0; i < N_W; ++i) s += urow[r][i] * h2w[i * 32 + o];
    xh[r][o] = s;
  }
  __syncthreads();
  int lane = t & 63, w = t >> 6;
  float ls = 0.f;
  for (int c = lane; c < 256; c += 64) {
    float v = (c < 32) ? xh[w][c] : urow[w][89 + c - 32];
    ls += v;
  }
  ls = waveSum(ls);
  if (lane == 0) inv[w] = 1.f / ls;
  __syncthreads();
  for (int idx = t; idx < 1024; idx += 256) {
    int r = idx >> 8, c = idx & 255;
    float v = (c < 32) ? xh[r][c] : urow[r][89 + c - 32];
    xout[(size_t)(b0 + r) * 256 + c] = v * inv[r];
  }
}

// ---------------- final tiny GEMM: xtemp = t[B,128] @ Wfb[128,5] + bfb ----------------
__global__ __launch_bounds__(256) void final5(
    const float* __restrict__ tb,
    const float* __restrict__ Wfb,
    const float* __restrict__ bfb,
    float* __restrict__ out)
{
  __shared__ float tt[32][129];
  __shared__ float wfb[5][128];
  int t = threadIdx.x;
  int b0 = blockIdx.x * 32;
  for (int idx = t; idx < 32 * 128; idx += 256) {
    int r = idx >> 7, c = idx & 127;
    tt[r][c] = tb[(size_t)(b0 + r) * 128 + c];
  }
  for (int idx = t; idx < 640; idx += 256) {
    int q = idx >> 7, j = idx & 127;
    wfb[q][j] = Wfb[j * 5 + q];
  }
  __syncthreads();
  if (t < 160) {
    int q = t >> 5, r = t & 31;
    float s = bfb[q];
    const float* wq = wfb[q];
    for (int j = 0; j < 128; ++j) s += tt[r][j] * wq[j];
    out[(size_t)(b0 + r) * 5 + q] = s;
  }
}

extern "C" void kernel_launch(void* const* d_in, const int* in_sizes, int n_in,
                              void* d_out, int out_size, void* d_ws, size_t ws_size,
                              hipStream_t stream)
{
  const float* pf   = (const float*)d_in[0];
  const float* wf   = (const float*)d_in[1];
  const int*   adj1 = (const int*)d_in[2];
  const int*   adj2 = (const int*)d_in[3];
  const float* uwa  = (const float*)d_in[4];
  const float* sent = (const float*)d_in[5];
  const float* w1   = (const float*)d_in[6];
  const float* as1  = (const float*)d_in[7];
  const float* ad1  = (const float*)d_in[8];
  const float* b1   = (const float*)d_in[9];
  const float* w2   = (const float*)d_in[10];
  const float* as2  = (const float*)d_in[11];
  const float* ad2  = (const float*)d_in[12];
  const float* b2   = (const float*)d_in[13];
  const float* Ws1  = (const float*)d_in[14];
  const float* bs1  = (const float*)d_in[15];
  const float* Ws2  = (const float*)d_in[16];
  const float* bs2  = (const float*)d_in[17];
  const float* Wf1  = (const float*)d_in[18];
  const float* bf1  = (const float*)d_in[19];
  const float* Wfa  = (const float*)d_in[20];
  const float* bfa  = (const float*)d_in[21];
  const float* Wfb  = (const float*)d_in[22];
  const float* bfb  = (const float*)d_in[23];

  float* ws = (float*)d_ws;
  float* wrm1 = ws;
  float* wrm2 = wrm1 + 65536;
  float* hp1  = wrm2 + 65536;
  float* hp2  = hp1 + (size_t)N_P * 256;
  float* es1v = hp2 + (size_t)N_ALLC * 256;
  float* ed1v = es1v + 8 * N_P;
  float* es2v = ed1v + 8 * N_P;
  float* ed2v = es2v + 8 * N_ALLC;
  float* h1wp = ed2v + 8 * N_ALLC;
  float* h2w  = h1wp + (size_t)N_ALLC * 256;
  float* o12  = h2w + N_W * 32;
  float* tbuf = o12 + (size_t)BQ * 256;
  float* parts = tbuf + (size_t)BQ * 128;                 // 4*2048*256 f32
  unsigned short* ws1pk = (unsigned short*)(parts + (size_t)4 * N_P * 256);
  unsigned short* ws2pk = ws1pk + 256 * 128;
  unsigned short* wf1pk = ws2pk + 768 * 128;
  unsigned short* wfapk = wf1pk + 128 * 64;

  float* out = (float*)d_out;
  float* out_o1n = out;                                   // [B][64]
  float* out_o2n = out + (size_t)BQ * 64;                 // [B][64]
  float* out_xt  = out + (size_t)BQ * 128;                // [B][5]
  float* out_app = out_xt + (size_t)BQ * 5;               // [8][2048][2048]
  float* out_awp = out_app + (size_t)8 * N_P * N_P;       // [8][2137][2137]
  float* out_x   = out_awp + (size_t)8 * N_ALLC * N_ALLC; // [B][256]

  repack_w<<<256, 256, 0, stream>>>(w1, wrm1);
  repack_w<<<256, 256, 0, stream>>>(w2, wrm2);
  repack_wpk<<<(256 * 128 + 255) / 256, 256, 0, stream>>>(Ws1, ws1pk, 256, 128);
  repack_wpk<<<(768 * 128 + 255) / 256, 256, 0, stream>>>(Ws2, ws2pk, 768, 128);
  repack_wpk<<<(128 * 64 + 255) / 256, 256, 0, stream>>>(Wf1, wf1pk, 128, 64);
  repack_wpk<<<(256 * 128 + 255) / 256, 256, 0, stream>>>(Wfa, wfapk, 256, 128);
  copy_word<<<89, 256, 0, stream>>>(wf, h1wp);

  // hp1 = pern_feature @ W1rm
  gemm_f32<<<dim3(32, 4), 256, 0, stream>>>(pf, 256, wrm1, 256, hp1, 256, nullptr, N_P, 256, 256, 0);
  esrc_edst<<<(N_P * 8 + 255) / 256, 256, 0, stream>>>(hp1, as1, ad1, es1v, ed1v, N_P);
  attn_softmax<<<dim3(8, N_P), 256, 0, stream>>>(es1v, ed1v, adj1, out_app, N_P);
  pv1_partial<<<dim3(16, 8, 4), 256, 0, stream>>>(out_app, hp1, parts);
  pv1_epilogue<<<N_P, 256, 0, stream>>>(parts, b1, h1wp);

  // hp2 = h1wp @ W2rm
  gemm_f32<<<dim3(34, 4), 256, 0, stream>>>(h1wp, 256, wrm2, 256, hp2, 256, nullptr, N_ALLC, 256, 256, 0);
  esrc_edst<<<(N_ALLC * 8 + 255) / 256, 256, 0, stream>>>(hp2, as2, ad2, es2v, ed2v, N_ALLC);
  attn_softmax<<<dim3(8, N_ALLC), 256, 0, stream>>>(es2v, ed2v, adj2, out_awp, N_ALLC);

  h2w_init<<<(N_W * 32 + 255) / 256, 256, 0, stream>>>(b2, h2w);
  pv2<<<dim3(N_W, 8), 256, 0, stream>>>(out_awp, hp2, h2w);

  xnorm_kernel<<<BQ / 4, 256, 0, stream>>>(uwa, h2w, out_x);

  // o1 = x @ W_s1 + b_s1 -> o12[:, :128]
  gemm_mfma<<<dim3(BQ / 64, 2), 256, 0, stream>>>(out_x, 256, ws1pk, 128, bs1, o12, 256, 256, 0);
  // o2 = sent @ W_s2 + b_s2 -> o12[:, 128:]
  gemm_mfma<<<dim3(BQ / 64, 2), 256, 0, stream>>>(sent, E2C, ws2pk, 128, bs2, o12 + 128, 256, E2C, 0);
  // output1_new = o1 @ W_f1 + b_f1
  gemm_mfma<<<dim3(BQ / 64, 1), 256, 0, stream>>>(o12, 256, wf1pk, 64, bf1, out_o1n, 64, 128, 0);
  // output2_new = o2 @ W_f1 + b_f1
  gemm_mfma<<<dim3(BQ / 64, 1), 256, 0, stream>>>(o12 + 128, 256, wf1pk, 64, bf1, out_o2n, 64, 128, 0);
  // t = relu(cat(o1,o2) @ W_fa + b_fa)
  gemm_mfma<<<dim3(BQ / 64, 2), 256, 0, stream>>>(o12, 256, wfapk, 128, bfa, tbuf, 128, 256, 1);
  // xtemp = t @ W_fb + b_fb
  final5<<<BQ / 32, 256, 0, stream>>>(tbuf, Wfb, bfb, out_xt);
}